// Round 1
// baseline (227.156 us; speedup 1.0000x reference)
//
#include <hip/hip_runtime.h>

// Walsh-Hadamard transform, N=4096 per row, fp32, scale 1/sqrt(4096)=1/64.
// H_4096 = H_16 (x) H_16 (x) H_16  -> three WHT16 passes over hex digits
// a=bits0-3, b=bits4-7, c=bits8-11, with two padded-LDS transposes between.

constexpr int N = 4096;
constexpr int LDS_STRIDE = 17;          // 16 + 1 pad: kills power-of-2 bank conflicts

__device__ __forceinline__ void wht16(float v[16]) {
#pragma unroll
    for (int m = 1; m < 16; m <<= 1) {
#pragma unroll
        for (int g = 0; g < 16; g += 2 * m) {
#pragma unroll
            for (int k = 0; k < m; ++k) {
                float a = v[g + k];
                float b = v[g + k + m];
                v[g + k]     = a + b;
                v[g + k + m] = a - b;
            }
        }
    }
}

__global__ __launch_bounds__(256, 4) void fwht4096_kernel(const float* __restrict__ in,
                                                          float* __restrict__ out) {
    // logical index within a row: e = c*256 + b*16 + a   (a,b,c in [0,16))
    // LDS physical map for a logical 256x16 tile: phys(i) = (i>>4)*17 + (i&15)
    __shared__ float lds[256 * LDS_STRIDE];

    const int t = threadIdx.x;
    const size_t row = blockIdx.x;
    const float* __restrict__ src = in + row * (size_t)N;
    float* __restrict__ dst = out + row * (size_t)N;

    float v[16];

    // ---- phase 1: thread t holds e = t*16 + j  (c=t>>4, b=t&15, a=j) ----
    {
        const float4* s4 = (const float4*)(src + t * 16);
        float4 f0 = s4[0], f1 = s4[1], f2 = s4[2], f3 = s4[3];
        v[0]=f0.x;  v[1]=f0.y;  v[2]=f0.z;  v[3]=f0.w;
        v[4]=f1.x;  v[5]=f1.y;  v[6]=f1.z;  v[7]=f1.w;
        v[8]=f2.x;  v[9]=f2.y;  v[10]=f2.z; v[11]=f2.w;
        v[12]=f3.x; v[13]=f3.y; v[14]=f3.z; v[15]=f3.w;
    }
    wht16(v);   // digit a done

    // ---- transpose 1: logical layout i = c*256 + a*16 + b ----
    // writer: i = (t>>4)*256 + j*16 + (t&15)  -> phys = ((t>>4)*16 + j)*17 + (t&15)
    {
        const int base = (t >> 4) * (16 * LDS_STRIDE) + (t & 15);
#pragma unroll
        for (int j = 0; j < 16; ++j) lds[base + j * LDS_STRIDE] = v[j];
    }
    __syncthreads();
    // reader: i = t*16 + p  (c=t>>4, a=t&15, b=p) -> phys = t*17 + p  (contiguous)
    {
        const int base = t * LDS_STRIDE;
#pragma unroll
        for (int p = 0; p < 16; ++p) v[p] = lds[base + p];
    }
    wht16(v);   // digit b done
    __syncthreads();   // protect LDS before overwrite

    // ---- transpose 2: logical layout i = b*256 + a*16 + c ----
    // writer: i = j*256 + (t&15)*16 + (t>>4) -> phys = (j*16 + (t&15))*17 + (t>>4)
    {
        const int base = (t & 15) * LDS_STRIDE + (t >> 4);
#pragma unroll
        for (int j = 0; j < 16; ++j) lds[base + j * (16 * LDS_STRIDE)] = v[j];
    }
    __syncthreads();
    // reader: i = t*16 + p  (b=t>>4, a=t&15, c=p) -> phys = t*17 + p
    {
        const int base = t * LDS_STRIDE;
#pragma unroll
        for (int p = 0; p < 16; ++p) v[p] = lds[base + p];
    }
    wht16(v);   // digit c done

    // ---- store: element e = p*256 + (t>>4)*16 + (t&15) = p*256 + t ----
    const float scale = 0.015625f;  // 1/64 = 1/sqrt(4096)
#pragma unroll
    for (int p = 0; p < 16; ++p) dst[p * 256 + t] = v[p] * scale;
}

extern "C" void kernel_launch(void* const* d_in, const int* in_sizes, int n_in,
                              void* d_out, int out_size, void* d_ws, size_t ws_size,
                              hipStream_t stream) {
    const float* x = (const float*)d_in[0];
    float* y = (float*)d_out;
    const int rows = in_sizes[0] / N;   // 4*2048 = 8192
    fwht4096_kernel<<<rows, 256, 0, stream>>>(x, y);
}